// Round 16
// baseline (332.243 us; speedup 1.0000x reference)
//
#include <hip/hip_runtime.h>
#include <stdint.h>

// Problem: B=32, S=2048, E2=1024, D=512
//   c[b][d]    = b_att[d] + sum_k dec[b][k] * W_att[1024+k][d]
//   att[b][s]  = sum_d tanh( sum_e x[b][s][e]*W_att[e][d] + c[b][d] ) * v[d]
//   w          = softmax(att, axis=s)
//   out[b][e]  = sum_s w[b][s] * x[b][s][e]
//
// ws layout: [0,256K) attention f32[65536]; [256K,320K) cbias f32[16384];
//            [320K,320K+1MiB) W_enc bf16 "fragment image":
//   16B unit index  u = c*2048 + wn*256 + nf*64 + lane   (c=K-chunk of 32)
//   holds W_enc[c*32 + (lane>>4)*8 + j][wn*64 + nf*16 + (lane&15)], j=0..7
// => wave wn's B-fragment for (c,nf) is ONE coalesced 1KB global load,
//    exactly in MFMA B-operand layout.

typedef __attribute__((ext_vector_type(8))) __bf16 bf16x8;
typedef __attribute__((ext_vector_type(4))) float f32x4;

__device__ __forceinline__ uint16_t f32_to_bf16_rne(float f) {
  union { float f; uint32_t u; } v; v.f = f;
  uint32_t u = v.u;
  return (uint16_t)((u + 0x7FFFu + ((u >> 16) & 1u)) >> 16);
}

// packed f32x2 -> bf16x2 (RNE), single HW instr on gfx950
__device__ __forceinline__ uint32_t cvtpk_bf16(float lo, float hi) {
  uint32_t r;
  asm("v_cvt_pk_bf16_f32 %0, %1, %2" : "=v"(r) : "v"(lo), "v"(hi));
  return r;
}

__device__ __forceinline__ bf16x8 cvt8(f32x4 lo, f32x4 hi) {
  union { uint32_t w[4]; bf16x8 v; } u;
  u.w[0] = cvtpk_bf16(lo.x, lo.y);
  u.w[1] = cvtpk_bf16(lo.z, lo.w);
  u.w[2] = cvtpk_bf16(hi.x, hi.y);
  u.w[3] = cvtpk_bf16(hi.z, hi.w);
  return u.v;
}

__device__ __forceinline__ float tanh_fast(float x) {
  float e = __expf(2.0f * x);
  return 1.0f - 2.0f * __builtin_amdgcn_rcpf(e + 1.0f);
}

// ---------------- Kernel A: prep (unchanged) ----------------
__global__ __launch_bounds__(256) void prep_kernel(
    const float* __restrict__ dec,   // (32,512)
    const float* __restrict__ Watt,  // (1536,512)
    const float* __restrict__ batt,  // (512)
    float* __restrict__ cbias,       // ws (32*512)
    uint16_t* __restrict__ Wb,       // ws (1 MiB fragment image)
    float* __restrict__ out)         // d_out (32768) -> zero
{
  const int t = blockIdx.x * 256 + threadIdx.x;  // [0,16384)

  for (int i = t; i < 32768; i += 16384) out[i] = 0.0f;

  {
    const int b = t >> 9, d = t & 511;
    const float* wd = Watt + 1024 * 512 + d;
    const float* dv = dec + b * 512;
    float s0 = 0.f, s1 = 0.f, s2 = 0.f, s3 = 0.f;
    #pragma unroll 4
    for (int k = 0; k < 512; k += 4) {
      s0 += dv[k + 0] * wd[(k + 0) * 512];
      s1 += dv[k + 1] * wd[(k + 1) * 512];
      s2 += dv[k + 2] * wd[(k + 2) * 512];
      s3 += dv[k + 3] * wd[(k + 3) * 512];
    }
    cbias[t] = batt[d] + ((s0 + s1) + (s2 + s3));
  }

  // W fragment image: 65536 16-byte units, 4 per thread.
  uint4* WbV = (uint4*)Wb;
  #pragma unroll
  for (int i = 0; i < 4; ++i) {
    const int u   = t + 16384 * i;    // [0,65536)
    const int c   = u >> 11;          // K-chunk
    const int rem = u & 2047;
    const int wn  = rem >> 8;         // 0..7
    const int nf  = (rem >> 6) & 3;   // 0..3
    const int ln  = rem & 63;         // lane
    const int kb  = c * 32 + ((ln >> 4) << 3);
    const int d   = wn * 64 + nf * 16 + (ln & 15);
    uint32_t h[8];
    #pragma unroll
    for (int kk = 0; kk < 8; ++kk) {
      float f = Watt[(size_t)(kb + kk) * 512 + d];
      h[kk] = f32_to_bf16_rne(f);
    }
    uint4 val;
    val.x = h[0] | (h[1] << 16);
    val.y = h[2] | (h[3] << 16);
    val.z = h[4] | (h[5] << 16);
    val.w = h[6] | (h[7] << 16);
    WbV[u] = val;
  }
}

// ---------------- Kernel B: fused energy GEMM + tanh + dot(v), v10 --------
// v10: ZERO barriers / ZERO LDS in the main loop. Each wave free-runs:
//  - A-fragments loaded DIRECTLY from x per lane (row = mf*16+l15,
//    k-octet = l4*8 -- the exact MFMA A mapping), cvt_pk f32->bf16 in reg.
//    All 8 waves of a block read identical A bytes -> L1 dedupes.
//  - B-fragments from the W image (v7 structure), dbuf one chunk ahead.
//  - No inter-wave coupling => compiler pipelines loads freely; TLP
//    (16 waves/CU) hides residual latency. LDS (256 B) only in epilogue.
// 1024 blocks x 512 thr; ~124 regs -> 4 waves/SIMD, 2 blocks/CU.
__global__ __launch_bounds__(512, 4) void energy_kernel(
    const float* __restrict__ x,       // (65536,1024)
    const uint16_t* __restrict__ Wb,   // fragment image (1 MiB)
    const float* __restrict__ cbias,   // (32,512)
    const float* __restrict__ vvec,    // (512)
    float* __restrict__ att)           // (65536), fully overwritten
{
  __shared__ float red[64];            // epilogue reduce only

  const int tid  = threadIdx.x;
  const int lane = tid & 63;
  const int wave = tid >> 6;           // 0..7 = wn (64-col group)
  const int l15  = lane & 15;
  const int l4   = lane >> 4;
  const int brow0 = blockIdx.x * 64;
  const int b     = brow0 >> 11;

  // per-lane A row bases (row = brow0 + mf*16 + l15, k-base = l4*8)
  const float* arow0 = x + (size_t)(brow0 + l15) * 1024 + l4 * 8;
  // this wave's B slice: 4 frags x 1 KB per chunk, chunk stride 32 KB
  const uint8_t* wslice = (const uint8_t*)Wb + (size_t)wave * 4096 + (size_t)lane * 16;

  f32x4 acc[4][4];
  #pragma unroll
  for (int mf = 0; mf < 4; ++mf)
    #pragma unroll
    for (int nf = 0; nf < 4; ++nf)
      acc[mf][nf] = (f32x4){0.f, 0.f, 0.f, 0.f};

  // B(0) prologue
  bf16x8 bA[4], bB[4];
  {
    const bf16x8* bs = (const bf16x8*)(wslice);
    bA[0] = bs[0]; bA[1] = bs[64]; bA[2] = bs[128]; bA[3] = bs[192];
  }

// One chunk: prefetch B(next) into BNXT; 4x { 2 f32x4 A-loads, cvt8, 4 MFMA }.
#define CHUNK(C, BCUR, BNXT)                                                   \
  {                                                                            \
    const int c_  = (C);                                                       \
    const int cn_ = (c_ + 1 < 32) ? c_ + 1 : 31;                               \
    {                                                                          \
      const bf16x8* bs_ = (const bf16x8*)(wslice + (size_t)cn_ * 32768);       \
      BNXT[0] = bs_[0];  BNXT[1] = bs_[64];                                    \
      BNXT[2] = bs_[128]; BNXT[3] = bs_[192];                                  \
    }                                                                          \
    _Pragma("unroll")                                                          \
    for (int mf = 0; mf < 4; ++mf) {                                           \
      const float* ap = arow0 + (size_t)mf * 16384 + c_ * 32;                  \
      f32x4 lo = *(const f32x4*)(ap);                                          \
      f32x4 hi = *(const f32x4*)(ap + 4);                                      \
      bf16x8 afm = cvt8(lo, hi);                                               \
      acc[mf][0] = __builtin_amdgcn_mfma_f32_16x16x32_bf16(afm, BCUR[0], acc[mf][0], 0, 0, 0); \
      acc[mf][1] = __builtin_amdgcn_mfma_f32_16x16x32_bf16(afm, BCUR[1], acc[mf][1], 0, 0, 0); \
      acc[mf][2] = __builtin_amdgcn_mfma_f32_16x16x32_bf16(afm, BCUR[2], acc[mf][2], 0, 0, 0); \
      acc[mf][3] = __builtin_amdgcn_mfma_f32_16x16x32_bf16(afm, BCUR[3], acc[mf][3], 0, 0, 0); \
    }                                                                          \
  }

  for (int c = 0; c < 32; c += 2) {
    CHUNK(c, bA, bB);
    CHUNK(c + 1, bB, bA);
  }
#undef CHUNK

  // ---- epilogue: tanh + dot(v); LDS-atomic reduce across the 8 waves ----
  float cb[4], vv[4];
  #pragma unroll
  for (int nf = 0; nf < 4; ++nf) {
    const int d = wave * 64 + nf * 16 + l15;
    cb[nf] = cbias[b * 512 + d];
    vv[nf] = vvec[d];
  }

  if (tid < 64) red[tid] = 0.0f;
  __syncthreads();

  #pragma unroll
  for (int mf = 0; mf < 4; ++mf) {
    float s[4] = {0.f, 0.f, 0.f, 0.f};
    #pragma unroll
    for (int nf = 0; nf < 4; ++nf) {
      #pragma unroll
      for (int j = 0; j < 4; ++j) {
        const float e = acc[mf][nf][j] + cb[nf];
        s[j] += tanh_fast(e) * vv[nf];
      }
    }
    #pragma unroll
    for (int j = 0; j < 4; ++j) {
      float r = s[j];
      r += __shfl_xor(r, 1);
      r += __shfl_xor(r, 2);
      r += __shfl_xor(r, 4);
      r += __shfl_xor(r, 8);
      if (l15 == 0) atomicAdd(&red[mf * 16 + 4 * l4 + j], r);
    }
  }
  __syncthreads();
  if (tid < 64) att[brow0 + tid] = red[tid];
}

// ---------------- Kernel C: softmax over S (in place) ----------------
__global__ __launch_bounds__(256) void softmax_kernel(float* __restrict__ att) {
  const int b = blockIdx.x;
  float* row = att + b * 2048;
  const int tid = threadIdx.x;
  __shared__ float redm[4], reds[4];

  float vals[8];
  float m = -1e30f;
  #pragma unroll
  for (int i = 0; i < 8; ++i) { vals[i] = row[tid + 256 * i]; m = fmaxf(m, vals[i]); }
  #pragma unroll
  for (int msk = 1; msk < 64; msk <<= 1) m = fmaxf(m, __shfl_xor(m, msk));
  if ((tid & 63) == 0) redm[tid >> 6] = m;
  __syncthreads();
  m = fmaxf(fmaxf(redm[0], redm[1]), fmaxf(redm[2], redm[3]));

  float s = 0.f;
  #pragma unroll
  for (int i = 0; i < 8; ++i) { vals[i] = __expf(vals[i] - m); s += vals[i]; }
  #pragma unroll
  for (int msk = 1; msk < 64; msk <<= 1) s += __shfl_xor(s, msk);
  if ((tid & 63) == 0) reds[tid >> 6] = s;
  __syncthreads();
  const float inv = 1.0f / (((reds[0] + reds[1]) + (reds[2] + reds[3])));
  #pragma unroll
  for (int i = 0; i < 8; ++i) row[tid + 256 * i] = vals[i] * inv;
}

// ---------------- Kernel D: context = w @ x ----------------
__global__ __launch_bounds__(256) void context_kernel(
    const float* __restrict__ x,   // (65536,1024)
    const float* __restrict__ w,   // (32,2048)
    float* __restrict__ out)       // (32,1024), pre-zeroed
{
  const int blk = blockIdx.x;
  const int b = blk >> 4, sc = blk & 15;
  const int tid = threadIdx.x;
  const float* xb = x + ((size_t)(b * 2048 + sc * 128)) * 1024 + tid * 4;
  const float* wb = w + b * 2048 + sc * 128;

  float4 acc = {0.f, 0.f, 0.f, 0.f};
  for (int si = 0; si < 128; ++si) {
    const float ww = wb[si];
    const float4 xv = *(const float4*)(xb + (size_t)si * 1024);
    acc.x += ww * xv.x;
    acc.y += ww * xv.y;
    acc.z += ww * xv.z;
    acc.w += ww * xv.w;
  }
  float* o = out + b * 1024 + tid * 4;
  atomicAdd(o + 0, acc.x);
  atomicAdd(o + 1, acc.y);
  atomicAdd(o + 2, acc.z);
  atomicAdd(o + 3, acc.w);
}

extern "C" void kernel_launch(void* const* d_in, const int* in_sizes, int n_in,
                              void* d_out, int out_size, void* d_ws, size_t ws_size,
                              hipStream_t stream) {
  const float* x    = (const float*)d_in[0];  // (32,2048,1024)
  const float* dec  = (const float*)d_in[1];  // (32,512)
  const float* Watt = (const float*)d_in[2];  // (1536,512)
  const float* batt = (const float*)d_in[3];  // (512)
  const float* v    = (const float*)d_in[4];  // (512)
  float* out = (float*)d_out;

  uint8_t* ws = (uint8_t*)d_ws;
  float*    att   = (float*)ws;                        // 256 KB
  float*    cbias = (float*)(ws + 256 * 1024);         // 64 KB
  uint16_t* Wb    = (uint16_t*)(ws + 320 * 1024);      // 1 MiB

  prep_kernel<<<64, 256, 0, stream>>>(dec, Watt, batt, cbias, Wb, out);
  energy_kernel<<<1024, 512, 0, stream>>>(x, Wb, cbias, v, att);
  softmax_kernel<<<32, 256, 0, stream>>>(att);
  context_kernel<<<512, 256, 0, stream>>>(x, att, out);
}

// Round 17
// 152.947 us; speedup vs baseline: 2.1723x; 2.1723x over previous
//
#include <hip/hip_runtime.h>
#include <stdint.h>

// Problem: B=32, S=2048, E2=1024, D=512
//   c[b][d]    = b_att[d] + sum_k dec[b][k] * W_att[1024+k][d]
//   att[b][s]  = sum_d tanh( sum_e x[b][s][e]*W_att[e][d] + c[b][d] ) * v[d]
//   w          = softmax(att, axis=s)
//   out[b][e]  = sum_s w[b][s] * x[b][s][e]
//
// ws layout: [0,256K) attention f32[65536]; [256K,320K) cbias f32[16384];
//            [320K,320K+1MiB) W_enc bf16 "fragment image":
//   16B unit index  u = c*2048 + wn*256 + nf*64 + lane   (c=K-chunk of 32)
//   holds W_enc[c*32 + (lane>>4)*8 + j][wn*64 + nf*16 + (lane&15)], j=0..7
// => wave wn's B-fragment for (c,nf) is ONE coalesced 1KB global load,
//    exactly in MFMA B-operand layout.

typedef __attribute__((ext_vector_type(8))) __bf16 bf16x8;
typedef __attribute__((ext_vector_type(4))) float f32x4;

__device__ __forceinline__ uint16_t f32_to_bf16_rne(float f) {
  union { float f; uint32_t u; } v; v.f = f;
  uint32_t u = v.u;
  return (uint16_t)((u + 0x7FFFu + ((u >> 16) & 1u)) >> 16);
}

__device__ __forceinline__ float tanh_fast(float x) {
  float e = __expf(2.0f * x);
  return 1.0f - 2.0f * __builtin_amdgcn_rcpf(e + 1.0f);
}

// ---------------- Kernel A: prep (unchanged) ----------------
__global__ __launch_bounds__(256) void prep_kernel(
    const float* __restrict__ dec,   // (32,512)
    const float* __restrict__ Watt,  // (1536,512)
    const float* __restrict__ batt,  // (512)
    float* __restrict__ cbias,       // ws (32*512)
    uint16_t* __restrict__ Wb,       // ws (1 MiB fragment image)
    float* __restrict__ out)         // d_out (32768) -> zero
{
  const int t = blockIdx.x * 256 + threadIdx.x;  // [0,16384)

  for (int i = t; i < 32768; i += 16384) out[i] = 0.0f;

  {
    const int b = t >> 9, d = t & 511;
    const float* wd = Watt + 1024 * 512 + d;
    const float* dv = dec + b * 512;
    float s0 = 0.f, s1 = 0.f, s2 = 0.f, s3 = 0.f;
    #pragma unroll 4
    for (int k = 0; k < 512; k += 4) {
      s0 += dv[k + 0] * wd[(k + 0) * 512];
      s1 += dv[k + 1] * wd[(k + 1) * 512];
      s2 += dv[k + 2] * wd[(k + 2) * 512];
      s3 += dv[k + 3] * wd[(k + 3) * 512];
    }
    cbias[t] = batt[d] + ((s0 + s1) + (s2 + s3));
  }

  // W fragment image: 65536 16-byte units, 4 per thread.
  uint4* WbV = (uint4*)Wb;
  #pragma unroll
  for (int i = 0; i < 4; ++i) {
    const int u   = t + 16384 * i;    // [0,65536)
    const int c   = u >> 11;          // K-chunk
    const int rem = u & 2047;
    const int wn  = rem >> 8;         // 0..7
    const int nf  = (rem >> 6) & 3;   // 0..3
    const int ln  = rem & 63;         // lane
    const int kb  = c * 32 + ((ln >> 4) << 3);
    const int d   = wn * 64 + nf * 16 + (ln & 15);
    uint32_t h[8];
    #pragma unroll
    for (int kk = 0; kk < 8; ++kk) {
      float f = Watt[(size_t)(kb + kk) * 512 + d];
      h[kk] = f32_to_bf16_rne(f);
    }
    uint4 val;
    val.x = h[0] | (h[1] << 16);
    val.y = h[2] | (h[3] << 16);
    val.z = h[4] | (h[5] << 16);
    val.w = h[6] | (h[7] << 16);
    WbV[u] = val;
  }
}

// ---------------- Kernel B: fused energy GEMM + tanh + dot(v), v12 --------
// v12 = v7 with the barrier amortized 4x: stage BK=128 (4 k-chunks) of A per
// barrier (4 coalesced float4/thread, LDS 2x16 KB dbuf), then free-run 4
// chunks {1 B-frag-group prefetch; 4x(ds_read af; setprio(1); 4 MFMA;
// setprio(0))} with NO barrier between chunks. B double-buffered per chunk
// in regs (v8's single-buffer mistake fixed). 8 barriers total vs 32.
// 1024 blocks x 512 thr (8 waves); ~125 regs -> 4 waves/SIMD, 2 blocks/CU.
__global__ __launch_bounds__(512, 4) void energy_kernel(
    const float* __restrict__ x,       // (65536,1024)
    const uint16_t* __restrict__ Wb,   // fragment image (1 MiB)
    const float* __restrict__ cbias,   // (32,512)
    const float* __restrict__ vvec,    // (512)
    float* __restrict__ att)           // (65536), fully overwritten
{
  __shared__ __align__(16) uint8_t AL[2][64 * 256];    // 2 x 16 KB : A 64r x 128k bf16

  const int tid  = threadIdx.x;
  const int lane = tid & 63;
  const int wave = tid >> 6;           // 0..7 = wn (64-col group)
  const int l15  = lane & 15;
  const int l4   = lane >> 4;
  const int brow0 = blockIdx.x * 64;
  const int b     = brow0 >> 11;

  // A staging: 4 float4/thread per stage. r_st = tid>>3, q_st = tid&7.
  // chunk kc: global float4 at asrc + i*128 + kc*32; LDS 8B unit at
  //   r_st*256 + ((kc*64 + q_st*8) ^ ((r_st&7)<<4))
  const int r_st = tid >> 3, q_st = tid & 7;
  int aoffs[4];
  #pragma unroll
  for (int kc = 0; kc < 4; ++kc)
    aoffs[kc] = r_st * 256 + ((kc * 64 + q_st * 8) ^ ((r_st & 7) << 4));
  const float* asrc = x + (size_t)(brow0 + r_st) * 1024 + q_st * 4;
  // this wave's B slice: 4 frags x 1 KB per chunk, chunk stride 32 KB
  const uint8_t* wslice = (const uint8_t*)Wb + (size_t)wave * 4096 + (size_t)lane * 16;

  f32x4 acc[4][4];
  #pragma unroll
  for (int mf = 0; mf < 4; ++mf)
    #pragma unroll
    for (int nf = 0; nf < 4; ++nf)
      acc[mf][nf] = (f32x4){0.f, 0.f, 0.f, 0.f};

  // prologue: av(stage 0) + B(chunk 0)
  f32x4 av[4];
  #pragma unroll
  for (int kc = 0; kc < 4; ++kc)
    av[kc] = __builtin_nontemporal_load((const f32x4*)(asrc + kc * 32));
  bf16x8 bA[4], bB[4];
  {
    const bf16x8* bs = (const bf16x8*)(wslice);
    bA[0] = bs[0]; bA[1] = bs[64]; bA[2] = bs[128]; bA[3] = bs[192];
  }

// One k-chunk (global chunk CG = 4*i + KC): prefetch B(CG+1) into BNXT,
// then 4 x { ds_read af[mf]; setprio(1); 4 MFMA vs BCUR; setprio(0) }.
#define DOCHUNK(I, KC, BCUR, BNXT)                                             \
  {                                                                            \
    const int cg_ = 4 * (I) + (KC);                                            \
    const int cn_ = (cg_ + 1 < 32) ? cg_ + 1 : 31;                             \
    {                                                                          \
      const bf16x8* bs_ = (const bf16x8*)(wslice + (size_t)cn_ * 32768);       \
      BNXT[0] = bs_[0];   BNXT[1] = bs_[64];                                   \
      BNXT[2] = bs_[128]; BNXT[3] = bs_[192];                                  \
    }                                                                          \
    _Pragma("unroll")                                                          \
    for (int mf = 0; mf < 4; ++mf) {                                           \
      const int r_ = mf * 16 + l15;                                            \
      bf16x8 afm = *(const bf16x8*)(Ab + r_ * 256 +                            \
                    (((KC) * 64 + l4 * 16) ^ ((r_ & 7) << 4)));                \
      __builtin_amdgcn_s_setprio(1);                                           \
      acc[mf][0] = __builtin_amdgcn_mfma_f32_16x16x32_bf16(afm, BCUR[0], acc[mf][0], 0, 0, 0); \
      acc[mf][1] = __builtin_amdgcn_mfma_f32_16x16x32_bf16(afm, BCUR[1], acc[mf][1], 0, 0, 0); \
      acc[mf][2] = __builtin_amdgcn_mfma_f32_16x16x32_bf16(afm, BCUR[2], acc[mf][2], 0, 0, 0); \
      acc[mf][3] = __builtin_amdgcn_mfma_f32_16x16x32_bf16(afm, BCUR[3], acc[mf][3], 0, 0, 0); \
      __builtin_amdgcn_s_setprio(0);                                           \
    }                                                                          \
  }

  for (int i = 0; i < 8; ++i) {        // 8 stages x BK=128
    uint8_t* Ab = AL[i & 1];

    // write A(stage i): 4 x 8B swizzled ds_write (compiler: counted vmcnt
    // waits av only -- av is older than any in-flight B in the FIFO)
    #pragma unroll
    for (int kc = 0; kc < 4; ++kc) {
      uint32_t lo = (uint32_t)f32_to_bf16_rne(av[kc].x) | ((uint32_t)f32_to_bf16_rne(av[kc].y) << 16);
      uint32_t hi = (uint32_t)f32_to_bf16_rne(av[kc].z) | ((uint32_t)f32_to_bf16_rne(av[kc].w) << 16);
      *(uint2*)(Ab + aoffs[kc]) = make_uint2(lo, hi);
    }
    if (i < 7) {                       // issue av(stage i+1); in flight across barrier
      #pragma unroll
      for (int kc = 0; kc < 4; ++kc)
        av[kc] = __builtin_nontemporal_load((const f32x4*)(asrc + (i + 1) * 128 + kc * 32));
    }
    asm volatile("s_waitcnt lgkmcnt(0)" ::: "memory");   // A writes (+ all ds) drained
    __builtin_amdgcn_s_barrier();
    asm volatile("" ::: "memory");

    // 4 chunks, no barriers in between; B dbuf alternates bA/bB
    DOCHUNK(i, 0, bA, bB);
    DOCHUNK(i, 1, bB, bA);
    DOCHUNK(i, 2, bA, bB);
    DOCHUNK(i, 3, bB, bA);
  }
#undef DOCHUNK

  // ---- epilogue: tanh + dot(v); LDS-atomic reduce across the 8 waves ----
  float cb[4], vv[4];
  #pragma unroll
  for (int nf = 0; nf < 4; ++nf) {
    const int d = wave * 64 + nf * 16 + l15;
    cb[nf] = cbias[b * 512 + d];
    vv[nf] = vvec[d];
  }

  __syncthreads();                       // all waves done with AL
  float* red = (float*)AL;               // reuse 256 B
  if (tid < 64) red[tid] = 0.0f;
  __syncthreads();

  #pragma unroll
  for (int mf = 0; mf < 4; ++mf) {
    float s[4] = {0.f, 0.f, 0.f, 0.f};
    #pragma unroll
    for (int nf = 0; nf < 4; ++nf) {
      #pragma unroll
      for (int j = 0; j < 4; ++j) {
        const float e = acc[mf][nf][j] + cb[nf];
        s[j] += tanh_fast(e) * vv[nf];
      }
    }
    #pragma unroll
    for (int j = 0; j < 4; ++j) {
      float r = s[j];
      r += __shfl_xor(r, 1);
      r += __shfl_xor(r, 2);
      r += __shfl_xor(r, 4);
      r += __shfl_xor(r, 8);
      if (l15 == 0) atomicAdd(&red[mf * 16 + 4 * l4 + j], r);
    }
  }
  __syncthreads();
  if (tid < 64) att[brow0 + tid] = red[tid];
}

// ---------------- Kernel C: softmax over S (in place) ----------------
__global__ __launch_bounds__(256) void softmax_kernel(float* __restrict__ att) {
  const int b = blockIdx.x;
  float* row = att + b * 2048;
  const int tid = threadIdx.x;
  __shared__ float redm[4], reds[4];

  float vals[8];
  float m = -1e30f;
  #pragma unroll
  for (int i = 0; i < 8; ++i) { vals[i] = row[tid + 256 * i]; m = fmaxf(m, vals[i]); }
  #pragma unroll
  for (int msk = 1; msk < 64; msk <<= 1) m = fmaxf(m, __shfl_xor(m, msk));
  if ((tid & 63) == 0) redm[tid >> 6] = m;
  __syncthreads();
  m = fmaxf(fmaxf(redm[0], redm[1]), fmaxf(redm[2], redm[3]));

  float s = 0.f;
  #pragma unroll
  for (int i = 0; i < 8; ++i) { vals[i] = __expf(vals[i] - m); s += vals[i]; }
  #pragma unroll
  for (int msk = 1; msk < 64; msk <<= 1) s += __shfl_xor(s, msk);
  if ((tid & 63) == 0) reds[tid >> 6] = s;
  __syncthreads();
  const float inv = 1.0f / (((reds[0] + reds[1]) + (reds[2] + reds[3])));
  #pragma unroll
  for (int i = 0; i < 8; ++i) row[tid + 256 * i] = vals[i] * inv;
}

// ---------------- Kernel D: context = w @ x ----------------
__global__ __launch_bounds__(256) void context_kernel(
    const float* __restrict__ x,   // (65536,1024)
    const float* __restrict__ w,   // (32,2048)
    float* __restrict__ out)       // (32,1024), pre-zeroed
{
  const int blk = blockIdx.x;
  const int b = blk >> 4, sc = blk & 15;
  const int tid = threadIdx.x;
  const float* xb = x + ((size_t)(b * 2048 + sc * 128)) * 1024 + tid * 4;
  const float* wb = w + b * 2048 + sc * 128;

  float4 acc = {0.f, 0.f, 0.f, 0.f};
  for (int si = 0; si < 128; ++si) {
    const float ww = wb[si];
    const float4 xv = *(const float4*)(xb + (size_t)si * 1024);
    acc.x += ww * xv.x;
    acc.y += ww * xv.y;
    acc.z += ww * xv.z;
    acc.w += ww * xv.w;
  }
  float* o = out + b * 1024 + tid * 4;
  atomicAdd(o + 0, acc.x);
  atomicAdd(o + 1, acc.y);
  atomicAdd(o + 2, acc.z);
  atomicAdd(o + 3, acc.w);
}

extern "C" void kernel_launch(void* const* d_in, const int* in_sizes, int n_in,
                              void* d_out, int out_size, void* d_ws, size_t ws_size,
                              hipStream_t stream) {
  const float* x    = (const float*)d_in[0];  // (32,2048,1024)
  const float* dec  = (const float*)d_in[1];  // (32,512)
  const float* Watt = (const float*)d_in[2];  // (1536,512)
  const float* batt = (const float*)d_in[3];  // (512)
  const float* v    = (const float*)d_in[4];  // (512)
  float* out = (float*)d_out;

  uint8_t* ws = (uint8_t*)d_ws;
  float*    att   = (float*)ws;                        // 256 KB
  float*    cbias = (float*)(ws + 256 * 1024);         // 64 KB
  uint16_t* Wb    = (uint16_t*)(ws + 320 * 1024);      // 1 MiB

  prep_kernel<<<64, 256, 0, stream>>>(dec, Watt, batt, cbias, Wb, out);
  energy_kernel<<<1024, 512, 0, stream>>>(x, Wb, cbias, v, att);
  softmax_kernel<<<32, 256, 0, stream>>>(att);
  context_kernel<<<512, 256, 0, stream>>>(x, att, out);
}

// Round 18
// 139.396 us; speedup vs baseline: 2.3835x; 1.0972x over previous
//
#include <hip/hip_runtime.h>
#include <stdint.h>

// Problem: B=32, S=2048, E2=1024, D=512
//   c[b][d]    = b_att[d] + sum_k dec[b][k] * W_att[1024+k][d]
//   att[b][s]  = sum_d tanh( sum_e x[b][s][e]*W_att[e][d] + c[b][d] ) * v[d]
//   w          = softmax(att, axis=s)
//   out[b][e]  = sum_s w[b][s] * x[b][s][e]
//
// ws layout: [0,256K) attention f32[65536]; [256K,320K) cbias f32[16384];
//            [320K,320K+1MiB) W_enc bf16 "fragment image":
//   16B unit index  u = c*2048 + wn*256 + nf*64 + lane   (c=K-chunk of 32)
//   holds W_enc[c*32 + (lane>>4)*8 + j][wn*64 + nf*16 + (lane&15)], j=0..7
// => wave wn's B-fragment for (c,nf) is ONE coalesced 1KB global load,
//    exactly in MFMA B-operand layout.

typedef __attribute__((ext_vector_type(8))) __bf16 bf16x8;
typedef __attribute__((ext_vector_type(4))) float f32x4;

__device__ __forceinline__ uint16_t f32_to_bf16_rne(float f) {
  union { float f; uint32_t u; } v; v.f = f;
  uint32_t u = v.u;
  return (uint16_t)((u + 0x7FFFu + ((u >> 16) & 1u)) >> 16);
}

__device__ __forceinline__ float tanh_fast(float x) {
  float e = __expf(2.0f * x);
  return 1.0f - 2.0f * __builtin_amdgcn_rcpf(e + 1.0f);
}

// ---------------- Kernel A: prep (unchanged) ----------------
__global__ __launch_bounds__(256) void prep_kernel(
    const float* __restrict__ dec,   // (32,512)
    const float* __restrict__ Watt,  // (1536,512)
    const float* __restrict__ batt,  // (512)
    float* __restrict__ cbias,       // ws (32*512)
    uint16_t* __restrict__ Wb,       // ws (1 MiB fragment image)
    float* __restrict__ out)         // d_out (32768) -> zero
{
  const int t = blockIdx.x * 256 + threadIdx.x;  // [0,16384)

  for (int i = t; i < 32768; i += 16384) out[i] = 0.0f;

  {
    const int b = t >> 9, d = t & 511;
    const float* wd = Watt + 1024 * 512 + d;
    const float* dv = dec + b * 512;
    float s0 = 0.f, s1 = 0.f, s2 = 0.f, s3 = 0.f;
    #pragma unroll 4
    for (int k = 0; k < 512; k += 4) {
      s0 += dv[k + 0] * wd[(k + 0) * 512];
      s1 += dv[k + 1] * wd[(k + 1) * 512];
      s2 += dv[k + 2] * wd[(k + 2) * 512];
      s3 += dv[k + 3] * wd[(k + 3) * 512];
    }
    cbias[t] = batt[d] + ((s0 + s1) + (s2 + s3));
  }

  // W fragment image: 65536 16-byte units, 4 per thread.
  uint4* WbV = (uint4*)Wb;
  #pragma unroll
  for (int i = 0; i < 4; ++i) {
    const int u   = t + 16384 * i;    // [0,65536)
    const int c   = u >> 11;          // K-chunk
    const int rem = u & 2047;
    const int wn  = rem >> 8;         // 0..7
    const int nf  = (rem >> 6) & 3;   // 0..3
    const int ln  = rem & 63;         // lane
    const int kb  = c * 32 + ((ln >> 4) << 3);
    const int d   = wn * 64 + nf * 16 + (ln & 15);
    uint32_t h[8];
    #pragma unroll
    for (int kk = 0; kk < 8; ++kk) {
      float f = Watt[(size_t)(kb + kk) * 512 + d];
      h[kk] = f32_to_bf16_rne(f);
    }
    uint4 val;
    val.x = h[0] | (h[1] << 16);
    val.y = h[2] | (h[3] << 16);
    val.z = h[4] | (h[5] << 16);
    val.w = h[6] | (h[7] << 16);
    WbV[u] = val;
  }
}

// ---------------- Kernel B: fused energy GEMM + tanh + dot(v), v13 --------
// v13: HALVE the B/L2 stream (the probe-identified binder: 1 GiB at BM=64,
// 2520 cyc/chunk/CU vs 1240 cyc of MFMA). Wave tile 128x64: acc[8][4]
// (128 VGPR) re-uses each B-fragment for 2x the rows => B traffic 512 MiB.
// BM=128, BN=512, BK=32. B in regs (dbuf 1 chunk ahead, v7-proven).
// LDS = A only: 128r x 32k bf16, dbuf 2x8 KB. 512 blocks x 512 thr (8 waves),
// lb(512,2): ~195 regs < 256-cap, 8 waves/CU, 1 block/CU.
__global__ __launch_bounds__(512, 2) void energy_kernel(
    const float* __restrict__ x,       // (65536,1024)
    const uint16_t* __restrict__ Wb,   // fragment image (1 MiB)
    const float* __restrict__ cbias,   // (32,512)
    const float* __restrict__ vvec,    // (512)
    float* __restrict__ att)           // (65536), fully overwritten
{
  __shared__ __align__(16) uint8_t AL[2][128 * 64];    // 2 x 8 KB

  const int tid  = threadIdx.x;
  const int lane = tid & 63;
  const int wave = tid >> 6;           // 0..7 = wn (64-col group)
  const int l15  = lane & 15;
  const int l4   = lane >> 4;
  const int brow0 = blockIdx.x * 128;
  const int b     = brow0 >> 11;

  // A staging: 2 x 8B units/thread (rows r_st and r_st+64, same q_st).
  // swz(r) = ((r>>1)&3)<<4 ; bit6 of r doesn't affect it => same for r+64.
  const int r_st = tid >> 3, q_st = tid & 7;
  const int swz  = ((r_st >> 1) & 3) << 4;
  const int aoff0 = r_st * 64 + ((q_st * 8) ^ swz);
  const int aoff1 = (r_st + 64) * 64 + ((q_st * 8) ^ swz);
  const float* asrc0 = x + (size_t)(brow0 + r_st) * 1024 + q_st * 4;
  const float* asrc1 = x + (size_t)(brow0 + r_st + 64) * 1024 + q_st * 4;
  // this wave's B slice: 4 frags x 1 KB per chunk, chunk stride 32 KB
  const uint8_t* wslice = (const uint8_t*)Wb + (size_t)wave * 4096 + (size_t)lane * 16;

  f32x4 acc[8][4];
  #pragma unroll
  for (int mf = 0; mf < 8; ++mf)
    #pragma unroll
    for (int nf = 0; nf < 4; ++nf)
      acc[mf][nf] = (f32x4){0.f, 0.f, 0.f, 0.f};

  // prologue: av(0) pair first (oldest in vmcnt FIFO), then B(0) frags
  f32x4 av0 = __builtin_nontemporal_load((const f32x4*)(asrc0));
  f32x4 av1 = __builtin_nontemporal_load((const f32x4*)(asrc1));
  bf16x8 bA[4], bB[4];
  {
    const bf16x8* bs = (const bf16x8*)(wslice);
    bA[0] = bs[0]; bA[1] = bs[64]; bA[2] = bs[128]; bA[3] = bs[192];
  }

// Per chunk c: ds_write A(c) [counted vmcnt retires av(c), which is OLDER
// than B(c) in the FIFO => B stays in flight]; issue av(c+1); lgkmcnt(0);
// s_barrier; issue B(c+1) into BNXT; 8x { ds_read af; 4 MFMA vs BCUR }.
// dbuf safety: past barrier(c) => all waves finished compute(c-1) => done
// reading AL[c&1] (written at c-2... read at c-1? AL[c&1] was last read by
// compute(c-1)? No: compute(c-1) reads AL[(c-1)&1]; AL[c&1] was last read
// by compute(c-2), finished before barrier(c-1) => safe at write A(c).
#define CHUNK(C, BCUR, BNXT)                                                   \
  {                                                                            \
    const int c_ = (C);                                                        \
    uint8_t* Ab = AL[c_ & 1];                                                  \
    {                                                                          \
      uint32_t lo = (uint32_t)f32_to_bf16_rne(av0.x) |                         \
                    ((uint32_t)f32_to_bf16_rne(av0.y) << 16);                  \
      uint32_t hi = (uint32_t)f32_to_bf16_rne(av0.z) |                         \
                    ((uint32_t)f32_to_bf16_rne(av0.w) << 16);                  \
      *(uint2*)(Ab + aoff0) = make_uint2(lo, hi);                              \
      lo = (uint32_t)f32_to_bf16_rne(av1.x) |                                  \
           ((uint32_t)f32_to_bf16_rne(av1.y) << 16);                           \
      hi = (uint32_t)f32_to_bf16_rne(av1.z) |                                  \
           ((uint32_t)f32_to_bf16_rne(av1.w) << 16);                           \
      *(uint2*)(Ab + aoff1) = make_uint2(lo, hi);                              \
    }                                                                          \
    const int cn_ = (c_ + 1 < 32) ? c_ + 1 : 31;                               \
    av0 = __builtin_nontemporal_load((const f32x4*)(asrc0 + cn_ * 32));        \
    av1 = __builtin_nontemporal_load((const f32x4*)(asrc1 + cn_ * 32));        \
    asm volatile("s_waitcnt lgkmcnt(0)" ::: "memory");                         \
    __builtin_amdgcn_s_barrier();                                              \
    asm volatile("" ::: "memory");                                             \
    {                                                                          \
      const bf16x8* bs_ = (const bf16x8*)(wslice + (size_t)cn_ * 32768);       \
      BNXT[0] = bs_[0];   BNXT[1] = bs_[64];                                   \
      BNXT[2] = bs_[128]; BNXT[3] = bs_[192];                                  \
    }                                                                          \
    _Pragma("unroll")                                                          \
    for (int mf = 0; mf < 8; ++mf) {                                           \
      const int r_ = mf * 16 + l15;                                            \
      bf16x8 afm = *(const bf16x8*)(Ab + r_ * 64 +                             \
                                    ((l4 * 16) ^ (((r_ >> 1) & 3) << 4)));     \
      acc[mf][0] = __builtin_amdgcn_mfma_f32_16x16x32_bf16(afm, BCUR[0], acc[mf][0], 0, 0, 0); \
      acc[mf][1] = __builtin_amdgcn_mfma_f32_16x16x32_bf16(afm, BCUR[1], acc[mf][1], 0, 0, 0); \
      acc[mf][2] = __builtin_amdgcn_mfma_f32_16x16x32_bf16(afm, BCUR[2], acc[mf][2], 0, 0, 0); \
      acc[mf][3] = __builtin_amdgcn_mfma_f32_16x16x32_bf16(afm, BCUR[3], acc[mf][3], 0, 0, 0); \
    }                                                                          \
  }

  for (int c = 0; c < 32; c += 2) {
    CHUNK(c, bA, bB);
    CHUNK(c + 1, bB, bA);
  }
#undef CHUNK

  // ---- epilogue: tanh + dot(v); LDS-atomic reduce across the 8 waves ----
  float cb[4], vv[4];
  #pragma unroll
  for (int nf = 0; nf < 4; ++nf) {
    const int d = wave * 64 + nf * 16 + l15;
    cb[nf] = cbias[b * 512 + d];
    vv[nf] = vvec[d];
  }

  __syncthreads();                       // all waves done with AL
  float* red = (float*)AL;               // reuse 512 B
  if (tid < 128) red[tid] = 0.0f;
  __syncthreads();

  #pragma unroll
  for (int mf = 0; mf < 8; ++mf) {
    float s[4] = {0.f, 0.f, 0.f, 0.f};
    #pragma unroll
    for (int nf = 0; nf < 4; ++nf) {
      #pragma unroll
      for (int j = 0; j < 4; ++j) {
        const float e = acc[mf][nf][j] + cb[nf];
        s[j] += tanh_fast(e) * vv[nf];
      }
    }
    #pragma unroll
    for (int j = 0; j < 4; ++j) {
      float r = s[j];
      r += __shfl_xor(r, 1);
      r += __shfl_xor(r, 2);
      r += __shfl_xor(r, 4);
      r += __shfl_xor(r, 8);
      if (l15 == 0) atomicAdd(&red[mf * 16 + 4 * l4 + j], r);
    }
  }
  __syncthreads();
  if (tid < 128) att[brow0 + tid] = red[tid];
}

// ---------------- Kernel C: softmax over S (in place) ----------------
__global__ __launch_bounds__(256) void softmax_kernel(float* __restrict__ att) {
  const int b = blockIdx.x;
  float* row = att + b * 2048;
  const int tid = threadIdx.x;
  __shared__ float redm[4], reds[4];

  float vals[8];
  float m = -1e30f;
  #pragma unroll
  for (int i = 0; i < 8; ++i) { vals[i] = row[tid + 256 * i]; m = fmaxf(m, vals[i]); }
  #pragma unroll
  for (int msk = 1; msk < 64; msk <<= 1) m = fmaxf(m, __shfl_xor(m, msk));
  if ((tid & 63) == 0) redm[tid >> 6] = m;
  __syncthreads();
  m = fmaxf(fmaxf(redm[0], redm[1]), fmaxf(redm[2], redm[3]));

  float s = 0.f;
  #pragma unroll
  for (int i = 0; i < 8; ++i) { vals[i] = __expf(vals[i] - m); s += vals[i]; }
  #pragma unroll
  for (int msk = 1; msk < 64; msk <<= 1) s += __shfl_xor(s, msk);
  if ((tid & 63) == 0) reds[tid >> 6] = s;
  __syncthreads();
  const float inv = 1.0f / (((reds[0] + reds[1]) + (reds[2] + reds[3])));
  #pragma unroll
  for (int i = 0; i < 8; ++i) row[tid + 256 * i] = vals[i] * inv;
}

// ---------------- Kernel D: context = w @ x ----------------
__global__ __launch_bounds__(256) void context_kernel(
    const float* __restrict__ x,   // (65536,1024)
    const float* __restrict__ w,   // (32,2048)
    float* __restrict__ out)       // (32,1024), pre-zeroed
{
  const int blk = blockIdx.x;
  const int b = blk >> 4, sc = blk & 15;
  const int tid = threadIdx.x;
  const float* xb = x + ((size_t)(b * 2048 + sc * 128)) * 1024 + tid * 4;
  const float* wb = w + b * 2048 + sc * 128;

  float4 acc = {0.f, 0.f, 0.f, 0.f};
  for (int si = 0; si < 128; ++si) {
    const float ww = wb[si];
    const float4 xv = *(const float4*)(xb + (size_t)si * 1024);
    acc.x += ww * xv.x;
    acc.y += ww * xv.y;
    acc.z += ww * xv.z;
    acc.w += ww * xv.w;
  }
  float* o = out + b * 1024 + tid * 4;
  atomicAdd(o + 0, acc.x);
  atomicAdd(o + 1, acc.y);
  atomicAdd(o + 2, acc.z);
  atomicAdd(o + 3, acc.w);
}

extern "C" void kernel_launch(void* const* d_in, const int* in_sizes, int n_in,
                              void* d_out, int out_size, void* d_ws, size_t ws_size,
                              hipStream_t stream) {
  const float* x    = (const float*)d_in[0];  // (32,2048,1024)
  const float* dec  = (const float*)d_in[1];  // (32,512)
  const float* Watt = (const float*)d_in[2];  // (1536,512)
  const float* batt = (const float*)d_in[3];  // (512)
  const float* v    = (const float*)d_in[4];  // (512)
  float* out = (float*)d_out;

  uint8_t* ws = (uint8_t*)d_ws;
  float*    att   = (float*)ws;                        // 256 KB
  float*    cbias = (float*)(ws + 256 * 1024);         // 64 KB
  uint16_t* Wb    = (uint16_t*)(ws + 320 * 1024);      // 1 MiB

  prep_kernel<<<64, 256, 0, stream>>>(dec, Watt, batt, cbias, Wb, out);
  energy_kernel<<<512, 512, 0, stream>>>(x, Wb, cbias, v, att);
  softmax_kernel<<<32, 256, 0, stream>>>(att);
  context_kernel<<<512, 256, 0, stream>>>(x, att, out);
}